// Round 13
// baseline (229.869 us; speedup 1.0000x reference)
//
#include <hip/hip_runtime.h>
#include <stdint.h>

// NSVF render. Round-19 = Round-18 (verified 225.0us, mlp=95us) + one
// attributable change: mlp_mfma LDS granule swizzle XOR -> ROTATION.
//  R14's N-split changed the A-read pattern but kept R12's XOR swizzle;
//  bank arithmetic for the current reads gives bank-group distribution
//  [4,8,10,16,12,8,4,0] (worst group 2x ideal) and 8-way b16 write
//  conflicts -- matching SQ_LDS_BANK_CONFLICT 8.52M (260 cyc/wave).
//  New: storage granule st = (d + 2*row) mod 16. Read bank-group =
//  (3*n16 + 4s + quad) mod 8; 3*n16 mod 8 is a permutation -> exactly 8
//  lanes/group = conflict-free b128 reads; writes 8-way -> 4-way.
//  Same values, only LDS placement -> bitwise-identical outputs.
//  Everything else byte-identical to R18.
//  (resubmitted unchanged after container-flake round)

#define NRAYS 8192
#define MAXS  64
#define EMB   32
#define HID   128
#define NPE   27
#define CH    64
#define NPTS  (NRAYS * MAXS)
#define RCAP  16384

// d_ws layout (float indices)
#define WS_WCOMB  0                        // [128][64] f32 (prep -> prep2)
#define WS_WPE    (WS_WCOMB + HID*CH)      // [32][64]
#define WS_BCOMB  (WS_WPE + 32*CH)         // [64]
#define WS_CCINIT (WS_BCOMB + CH)          // [8192][64]
#define WS_COUNTS (WS_CCINIT + NRAYS*CH)   // [8192] int (unused now)
#define WS_OFFS   (WS_COUNTS + NRAYS)      // [8192] int (unused now)
#define WS_TOTAL  (WS_OFFS + NRAYS)        // [1] int (atomic total)
#define WS_RCNT   (WS_TOTAL + 1)           // [1] int
#define WS_LIST   (WS_TOTAL + 4)           // [NPTS] int (16B aligned)
#define WS_PTOUT  (WS_LIST + NPTS)         // [NPTS] float4
#define WS_FRAGS  (WS_PTOUT + 4*NPTS)      // 56*2*64*4 ints
#define WS_RLIST  (WS_FRAGS + 56*2*64*4)   // [RCAP] int
#define WS_PTSC   (WS_RLIST + RCAP)        // [NPTS] float4 (16B aligned)

typedef __attribute__((ext_vector_type(8))) short bf16x8;
typedef __attribute__((ext_vector_type(4))) float f32x4;
union FI { int i[4]; int4 v; bf16x8 f; };

#define MFMA16(a, b, c) __builtin_amdgcn_mfma_f32_16x16x32_bf16(a, b, c, 0, 0, 0)

__device__ __forceinline__ f32x4 mfma3(bf16x8 ah, bf16x8 al, bf16x8 bh, bf16x8 bl,
                                       f32x4 c) {
  c = MFMA16(al, bh, c);
  c = MFMA16(ah, bl, c);
  c = MFMA16(ah, bh, c);
  return c;
}

// 2-pass: A is bf16-only, B stays hi/lo split
__device__ __forceinline__ f32x4 mfma2(bf16x8 ah, bf16x8 bh, bf16x8 bl, f32x4 c) {
  c = MFMA16(ah, bl, c);
  c = MFMA16(ah, bh, c);
  return c;
}

__device__ __forceinline__ void split8(const float* x, bf16x8& hi, bf16x8& lo) {
  FI H, L;
#pragma unroll
  for (int r = 0; r < 4; ++r) {
    unsigned u0 = __float_as_uint(x[2 * r]);
    unsigned u1 = __float_as_uint(x[2 * r + 1]);
    unsigned h0 = u0 & 0xffff0000u, h1 = u1 & 0xffff0000u;
    unsigned l0 = __float_as_uint(x[2 * r] - __uint_as_float(h0));
    unsigned l1 = __float_as_uint(x[2 * r + 1] - __uint_as_float(h1));
    H.i[r] = (int)((h0 >> 16) | (h1 & 0xffff0000u));
    L.i[r] = (int)((l0 >> 16) | (l1 & 0xffff0000u));
  }
  hi = H.f; lo = L.f;
}

// round-to-nearest-even bf16 (relu outputs: finite, non-NaN)
__device__ __forceinline__ unsigned short bf16rne(float v) {
  unsigned u = __float_as_uint(v);
  return (unsigned short)((u + 0x7fffu + ((u >> 16) & 1u)) >> 16);
}

// ---------------- prep: Wcomb f32 + PE tables + counter zero ----------------
__global__ __launch_bounds__(256) void prep_kernel(
    const float* __restrict__ Wfeat, const float* __restrict__ bfeat,
    const float* __restrict__ Wc1, const float* __restrict__ bc1,
    float* __restrict__ ws) {
  int idx = blockIdx.x * 256 + threadIdx.x;
  if (idx < HID * CH) {                        // Wcomb f32 (m-major), 8192-way
    int m = idx >> 6, j = idx & 63;
    float s = 0.f;
    for (int f = 0; f < HID; ++f) s = fmaf(Wfeat[m * HID + f], Wc1[f * CH + j], s);
    ws[WS_WCOMB + idx] = s;
    return;
  }
  idx -= HID * CH;
  if (idx < 32 * CH) {                         // WPE v-major [v][j]
    int v = idx >> 6, j = idx & 63;
    ws[WS_WPE + idx] = (v < NPE) ? Wc1[(HID + v) * CH + j] : 0.f;
    return;
  }
  idx -= 32 * CH;
  if (idx < CH) {                              // bcomb
    float s = bc1[idx];
    for (int f = 0; f < HID; ++f) s = fmaf(bfeat[f], Wc1[f * CH + idx], s);
    ws[WS_BCOMB + idx] = s;
    return;
  }
  idx -= CH;
  if (idx < 2) ((int*)(ws + WS_TOTAL))[idx] = 0;  // TOTAL (atomic base) + RCNT
}

// build bf16 hi/lo B-fragments: frag elem j of lane (n16,quad) = B[k0+j][n]
__global__ __launch_bounds__(256) void prep2_kernel(
    const float* __restrict__ W1, const float* __restrict__ W2,
    float* __restrict__ ws) {
  int t = blockIdx.x * 256 + threadIdx.x;
  if (t >= 56 * 64) return;
  const int fid = t >> 6, lane = t & 63;
  const int n16 = lane & 15, quad = lane >> 4;
  float x[8];
  if (fid < 8) {                       // L1: W1[k][n], K=32
    const int n = fid * 16 + n16, k0 = quad * 8;
#pragma unroll
    for (int j = 0; j < 8; ++j) x[j] = W1[(k0 + j) * HID + n];
  } else if (fid < 40) {               // L2: fid = 8 + nt*4 + s
    const int f = fid - 8, nt = f >> 2, s = f & 3;
    const int n = nt * 16 + n16, k0 = s * 32 + quad * 8;
#pragma unroll
    for (int j = 0; j < 8; ++j) x[j] = W2[(k0 + j) * HID + n];
  } else {                             // Wcomb: fid = 40 + nt*4 + s
    const int f = fid - 40, nt = f >> 2, s = f & 3;
    const int n = nt * 16 + n16, k0 = s * 32 + quad * 8;
#pragma unroll
    for (int j = 0; j < 8; ++j) x[j] = ws[WS_WCOMB + (k0 + j) * CH + n];
  }
  FI H, L;
#pragma unroll
  for (int r = 0; r < 4; ++r) {
    unsigned u0 = __float_as_uint(x[2 * r]);
    unsigned u1 = __float_as_uint(x[2 * r + 1]);
    unsigned h0 = u0 & 0xffff0000u, h1 = u1 & 0xffff0000u;
    unsigned l0 = __float_as_uint(x[2 * r] - __uint_as_float(h0));
    unsigned l1 = __float_as_uint(x[2 * r + 1] - __uint_as_float(h1));
    H.i[r] = (int)((h0 >> 16) | (h1 & 0xffff0000u));
    L.i[r] = (int)((l0 >> 16) | (l1 & 0xffff0000u));
  }
  int4* o = (int4*)(ws + WS_FRAGS);
  o[(fid * 2 + 0) * 64 + lane] = H.v;
  o[(fid * 2 + 1) * 64 + lane] = L.v;
}

// ------- fused build: ballot count + block scan + 1 atomic/block +
//         compacted list/ptsc gather + per-ray view-PE -------------------
__global__ __launch_bounds__(1024) void build_kernel(
    const float* __restrict__ rays_d, const int* __restrict__ p2v,
    const float* __restrict__ pts, float* __restrict__ ws) {
  __shared__ int wcnt[16];
  __shared__ int wbase[16];
  const int tid = threadIdx.x;
  const int wv = tid >> 6, lane = tid & 63;
  const int ray = blockIdx.x * 16 + wv;
  const int pidx = ray * MAXS + lane;
  const int gidx = p2v[pidx];
  const bool valid = gidx >= 0;
  const unsigned long long ball = __ballot(valid);
  const int cnt = __popcll(ball);
  const int rank = __popcll(ball & ((1ull << lane) - 1ull));
  if (lane == 0) wcnt[wv] = cnt;
  __syncthreads();
  if (tid < 16) {                      // wave 0, lanes 0..15: scan 16 counts
    const int c = wcnt[tid];
    int inc = c;
#pragma unroll
    for (int off = 1; off < 16; off <<= 1) {
      const int u = __shfl_up(inc, off, 64);
      if (tid >= off) inc += u;
    }
    const int excl = inc - c;
    const int btot = __shfl(inc, 15, 64);
    int gbase = 0;
    if (tid == 0) gbase = atomicAdd((int*)(ws + WS_TOTAL), btot);
    gbase = __shfl(gbase, 0, 64);
    wbase[tid] = gbase + excl;
  }
  __syncthreads();
  if (valid) {
    const int slot = wbase[wv] + rank;
    ((int*)(ws + WS_LIST))[slot] = pidx;
    float4 pc;
    pc.x = pts[pidx * 3 + 0];
    pc.y = pts[pidx * 3 + 1];
    pc.z = pts[pidx * 3 + 2];
    pc.w = __int_as_float(gidx);
    ((float4*)(ws + WS_PTSC))[slot] = pc;
  }

  // per-ray view-PE -> ccinit[ray][lane] (identical math to count_pe)
  const float d0 = rays_d[ray * 3 + 0];
  const float d1 = rays_d[ray * 3 + 1];
  const float d2 = rays_d[ray * 3 + 2];
  float vemb[NPE];
  vemb[0] = d0; vemb[1] = d1; vemb[2] = d2;
#pragma unroll
  for (int i = 0; i < 3; ++i) {
    const float di = (i == 0) ? d0 : (i == 1) ? d1 : d2;
#pragma unroll
    for (int l = 0; l < 4; ++l) {
      const float ang = di * (float)(1 << l);
      vemb[3 + i * 4 + l] = __sinf(ang);
      vemb[3 + 12 + i * 4 + l] = __cosf(ang);
    }
  }
  float s = ws[WS_BCOMB + lane];
  const float* wpe = ws + WS_WPE;
#pragma unroll
  for (int vv = 0; vv < NPE; ++vv) s = fmaf(vemb[vv], wpe[vv * CH + lane], s);
  ws[WS_CCINIT + ray * CH + lane] = s;
}

// ---------------- MFMA MLP (4 waves, M=64, N-split) ----------------
__device__ __forceinline__ void ve_frag(const float* __restrict__ vox_emb,
                                        const float* __restrict__ Wpts,
                                        float4 pc, int quad,
                                        bf16x8& hi, bf16x8& lo) {
  float x[8];
  const int gidx = __float_as_int(pc.w);
  const float4* vr = (const float4*)vox_emb + gidx * 8 + quad * 2;
  const float4 va = vr[0], vb = vr[1];
  const float px = pc.x, py = pc.y, pz = pc.z;
  const float4* wp = (const float4*)Wpts;
  const float4 wa0 = wp[quad * 2 + 0], wa1 = wp[quad * 2 + 1];
  const float4 wb0 = wp[8 + quad * 2 + 0], wb1 = wp[8 + quad * 2 + 1];
  const float4 wc0 = wp[16 + quad * 2 + 0], wc1 = wp[16 + quad * 2 + 1];
  x[0] = va.x + fmaf(px, wa0.x, fmaf(py, wb0.x, pz * wc0.x));
  x[1] = va.y + fmaf(px, wa0.y, fmaf(py, wb0.y, pz * wc0.y));
  x[2] = va.z + fmaf(px, wa0.z, fmaf(py, wb0.z, pz * wc0.z));
  x[3] = va.w + fmaf(px, wa0.w, fmaf(py, wb0.w, pz * wc0.w));
  x[4] = vb.x + fmaf(px, wa1.x, fmaf(py, wb1.x, pz * wc1.x));
  x[5] = vb.y + fmaf(px, wa1.y, fmaf(py, wb1.y, pz * wc1.y));
  x[6] = vb.z + fmaf(px, wa1.z, fmaf(py, wb1.z, pz * wc1.z));
  x[7] = vb.w + fmaf(px, wa1.w, fmaf(py, wb1.w, pz * wc1.w));
  split8(x, hi, lo);
}

// bf16 activation LDS: 64 rows x 136 shorts (17 granules of 8 shorts; 16 used)
// data granule d of row stored at granule st = (d + 2*row) mod 16
// => read bank-group (3*n16 + 4s + quad) mod 8: uniform (conflict-free)
#define SROW 136

__global__ __launch_bounds__(256, 4) void mlp_mfma(
    const float* __restrict__ vox_emb, const float* __restrict__ Wpts,
    const float* __restrict__ b1, const float* __restrict__ b2,
    const float* __restrict__ Wsig, const float* __restrict__ bsig,
    const float* __restrict__ Wc2, const float* __restrict__ bc2,
    float* __restrict__ ws) {
  __shared__ __align__(16) unsigned short alds[64 * SROW];
  __shared__ float sgp[4][64];
  __shared__ __align__(16) float4 rgbp[4][64];
  const int tid = threadIdx.x;
  const int wave = tid >> 6, lane = tid & 63;
  const int n16 = lane & 15, quad = lane >> 4;
  const int total = ((const int*)(ws + WS_TOTAL))[0];
  const int base = blockIdx.x * 64;
  if (base >= total) return;
  const int* list = (const int*)(ws + WS_LIST);

  // point ids + coords for all 4 m-slots (block covers 64 points)
  int pidx[4]; float4 pc[4];
#pragma unroll
  for (int m = 0; m < 4; ++m) {
    const int slot = min(base + m * 16 + n16, total - 1);
    pidx[m] = list[slot];
    pc[m] = ((const float4*)(ws + WS_PTSC))[slot];
  }
  const int4* fb = (const int4*)(ws + WS_FRAGS);
  const int nt0 = 2 * wave, nt1 = nt0 + 1;   // this wave's L1/L2 N-slice

  // ---- L1 B frags for this wave's 2 nt tiles (hi+lo)
  int4 B1[4];
  B1[0] = fb[(nt0 * 2 + 0) * 64 + lane];
  B1[1] = fb[(nt0 * 2 + 1) * 64 + lane];
  B1[2] = fb[(nt1 * 2 + 0) * 64 + lane];
  B1[3] = fb[(nt1 * 2 + 1) * 64 + lane];

  // ---- A (ve) fragments for all 4 m-slots (gathers fly with B1)
  bf16x8 ah[4], al[4];
#pragma unroll
  for (int m = 0; m < 4; ++m) ve_frag(vox_emb, Wpts, pc[m], quad, ah[m], al[m]);

  // ---- prefetch L2 s=0
  int4 BL[4];
  BL[0] = fb[((8 + nt0 * 4) * 2 + 0) * 64 + lane];
  BL[1] = fb[((8 + nt0 * 4) * 2 + 1) * 64 + lane];
  BL[2] = fb[((8 + nt1 * 4) * 2 + 0) * 64 + lane];
  BL[3] = fb[((8 + nt1 * 4) * 2 + 1) * 64 + lane];

  // ---- L1: h1[:, wave cols] for 64 pts (3-pass, A = f32 split)
  f32x4 h[4][2];
  {
    const float ba = b1[nt0 * 16 + n16], bb = b1[nt1 * 16 + n16];
#pragma unroll
    for (int m = 0; m < 4; ++m) {
      h[m][0] = (f32x4){ba, ba, ba, ba};
      h[m][1] = (f32x4){bb, bb, bb, bb};
    }
  }
  {
    FI H0, L0, H1, L1v;
    H0.v = B1[0]; L0.v = B1[1]; H1.v = B1[2]; L1v.v = B1[3];
#pragma unroll
    for (int m = 0; m < 4; ++m) {
      h[m][0] = mfma3(ah[m], al[m], H0.f, L0.f, h[m][0]);
      h[m][1] = mfma3(ah[m], al[m], H1.f, L1v.f, h[m][1]);
    }
  }
#pragma unroll
  for (int m = 0; m < 4; ++m)
#pragma unroll
    for (int j = 0; j < 2; ++j) {
      const int nt = nt0 + j;
#pragma unroll
      for (int r = 0; r < 4; ++r) {
        const float v = fmaxf(h[m][j][r], 0.f);
        const int row = m * 16 + quad * 4 + r;
        const int st = (2 * nt + (n16 >> 3) + 2 * row) & 15;
        alds[row * SROW + (st << 3) + (n16 & 7)] = bf16rne(v);
      }
    }
  __syncthreads();   // h1 complete (all cols, all rows)

  // ---- L2: g[:, wave cols] for 64 pts, A = bf16 from LDS, K=128
  f32x4 g[4][2];
  {
    const float ba = b2[nt0 * 16 + n16], bb = b2[nt1 * 16 + n16];
#pragma unroll
    for (int m = 0; m < 4; ++m) {
      g[m][0] = (f32x4){ba, ba, ba, ba};
      g[m][1] = (f32x4){bb, bb, bb, bb};
    }
  }
#pragma unroll
  for (int s = 0; s < 4; ++s) {
    // st = (d + 2*row) & 15 with d = 4s+quad, row = m*16+n16 -> m-independent
    const int st = (4 * s + quad + 2 * n16) & 15;
    FI H0, L0, H1, L1v;
    H0.v = BL[0]; L0.v = BL[1]; H1.v = BL[2]; L1v.v = BL[3];
#pragma unroll
    for (int m = 0; m < 4; ++m) {
      const bf16x8 A = *(const bf16x8*)&alds[(m * 16 + n16) * SROW + (st << 3)];
      g[m][0] = mfma2(A, H0.f, L0.f, g[m][0]);
      g[m][1] = mfma2(A, H1.f, L1v.f, g[m][1]);
    }
    if (s < 3) {
      BL[0] = fb[((8 + nt0 * 4 + s + 1) * 2 + 0) * 64 + lane];
      BL[1] = fb[((8 + nt0 * 4 + s + 1) * 2 + 1) * 64 + lane];
      BL[2] = fb[((8 + nt1 * 4 + s + 1) * 2 + 0) * 64 + lane];
      BL[3] = fb[((8 + nt1 * 4 + s + 1) * 2 + 1) * 64 + lane];
    }
  }

  // ---- overlap global work with the pre-h2 barrier:
  // color B (nt = wave, all 4 s), pm shuffles, ccinit gathers
  int4 BC[8];
#pragma unroll
  for (int s = 0; s < 4; ++s) {
    BC[2 * s]     = fb[((40 + wave * 4 + s) * 2 + 0) * 64 + lane];
    BC[2 * s + 1] = fb[((40 + wave * 4 + s) * 2 + 1) * 64 + lane];
  }
  int pm[4][4];
#pragma unroll
  for (int m = 0; m < 4; ++m)
#pragma unroll
    for (int r = 0; r < 4; ++r)
      pm[m][r] = __shfl(pidx[m], quad * 4 + r, 64);
  f32x4 cacc[4];
#pragma unroll
  for (int m = 0; m < 4; ++m)
#pragma unroll
    for (int r = 0; r < 4; ++r)
      cacc[m][r] = ws[WS_CCINIT + (pm[m][r] >> 6) * CH + wave * 16 + n16];

  __syncthreads();   // all waves done READING h1 -> safe to overwrite with h2

  // ---- sigma partials (this wave's 32 cols) + write h2
  float sgv[4][4];
#pragma unroll
  for (int m = 0; m < 4; ++m)
#pragma unroll
    for (int r = 0; r < 4; ++r) sgv[m][r] = 0.f;
  {
    const float sv0 = Wsig[nt0 * 16 + n16], sv1 = Wsig[nt1 * 16 + n16];
#pragma unroll
    for (int m = 0; m < 4; ++m)
#pragma unroll
      for (int j = 0; j < 2; ++j) {
        const int nt = nt0 + j;
        const float sv = j ? sv1 : sv0;
#pragma unroll
        for (int r = 0; r < 4; ++r) {
          const float v = fmaxf(g[m][j][r], 0.f);
          sgv[m][r] = fmaf(v, sv, sgv[m][r]);
          const int row = m * 16 + quad * 4 + r;
          const int st = (2 * nt + (n16 >> 3) + 2 * row) & 15;
          alds[row * SROW + (st << 3) + (n16 & 7)] = bf16rne(v);
        }
      }
  }
#pragma unroll
  for (int mask = 1; mask < 16; mask <<= 1)
#pragma unroll
    for (int m = 0; m < 4; ++m)
#pragma unroll
      for (int r = 0; r < 4; ++r)
        sgv[m][r] += __shfl_xor(sgv[m][r], mask, 64);
  if (n16 == 0) {
#pragma unroll
    for (int m = 0; m < 4; ++m)
#pragma unroll
      for (int r = 0; r < 4; ++r)
        sgp[wave][m * 16 + quad * 4 + r] = sgv[m][r];
  }
  __syncthreads();   // h2 + sigma partials ready

  // ---- color: cc[:, wave*16..+16) = ccinit + h2 @ Wcomb slice
#pragma unroll
  for (int s = 0; s < 4; ++s) {
    const int st = (4 * s + quad + 2 * n16) & 15;
    FI H, L;
    H.v = BC[2 * s]; L.v = BC[2 * s + 1];
#pragma unroll
    for (int m = 0; m < 4; ++m) {
      const bf16x8 A = *(const bf16x8*)&alds[(m * 16 + n16) * SROW + (st << 3)];
      cacc[m] = mfma2(A, H.f, L.f, cacc[m]);
    }
  }

  // ---- rgb partials from this wave's 16 cols
  {
    const int j = wave * 16 + n16;
    const float w0 = Wc2[j * 3 + 0], w1c = Wc2[j * 3 + 1], w2c = Wc2[j * 3 + 2];
#pragma unroll
    for (int m = 0; m < 4; ++m) {
      float c0[4], c1[4], c2[4];
#pragma unroll
      for (int r = 0; r < 4; ++r) {
        const float cv = fmaxf(cacc[m][r], 0.f);
        c0[r] = cv * w0; c1[r] = cv * w1c; c2[r] = cv * w2c;
      }
#pragma unroll
      for (int mask = 1; mask < 16; mask <<= 1)
#pragma unroll
        for (int r = 0; r < 4; ++r) {
          c0[r] += __shfl_xor(c0[r], mask, 64);
          c1[r] += __shfl_xor(c1[r], mask, 64);
          c2[r] += __shfl_xor(c2[r], mask, 64);
        }
      if (n16 == 0) {
#pragma unroll
        for (int r = 0; r < 4; ++r)
          rgbp[wave][m * 16 + quad * 4 + r] = make_float4(c0[r], c1[r], c2[r], 0.f);
      }
    }
  }
  __syncthreads();   // rgb partials ready

  // ---- final: wave owns its own m = wave points
  const int pidw = (wave == 0) ? pidx[0] : (wave == 1) ? pidx[1]
                 : (wave == 2) ? pidx[2] : pidx[3];
  int pmw[4];
#pragma unroll
  for (int r = 0; r < 4; ++r) pmw[r] = __shfl(pidw, quad * 4 + r, 64);

  if (n16 == 0) {
    const float bs = bsig[0];
    const float bcr = bc2[0], bcg = bc2[1], bcb = bc2[2];
#pragma unroll
    for (int r = 0; r < 4; ++r) {
      const int ptl = wave * 16 + quad * 4 + r;
      if (base + ptl < total) {
        const int pid = pmw[r];
        const float sig = sgp[0][ptl] + sgp[1][ptl] + sgp[2][ptl] + sgp[3][ptl] + bs;
        const float4 r0 = rgbp[0][ptl], r1 = rgbp[1][ptl];
        const float4 r2 = rgbp[2][ptl], r3 = rgbp[3][ptl];
        ((float4*)(ws + WS_PTOUT))[pid] = make_float4(
            sig,
            r0.x + r1.x + r2.x + r3.x + bcr,
            r0.y + r1.y + r2.y + r3.y + bcg,
            r0.z + r1.z + r2.z + r3.z + bcb);
        if (fabsf(sig) < 0.006f) {
          const int ri = atomicAdd((int*)(ws + WS_RCNT), 1);
          if (ri < RCAP) ((int*)(ws + WS_RLIST))[ri] = pid;
        }
      }
    }
  }
}

// ------- sigma repair: wave-per-4-points, shared W1/W2 row loads -------
__device__ __forceinline__ float wave_sum(float v) {
#pragma unroll
  for (int off = 32; off > 0; off >>= 1) v += __shfl_down(v, off, 64);
  return v;
}

__global__ __launch_bounds__(256) void repair_kernel(
    const float* __restrict__ pts, const int* __restrict__ p2v,
    const float* __restrict__ vox_emb, const float* __restrict__ Wpts,
    const float* __restrict__ W1, const float* __restrict__ b1,
    const float* __restrict__ W2, const float* __restrict__ b2,
    const float* __restrict__ Wsig, const float* __restrict__ bsig,
    float* __restrict__ ws) {
  // per-wave LDS slices (wave-coherent, no block barriers needed)
  __shared__ float velds[4][4][EMB];    // [wave][point][32]
  __shared__ float h1lds[4][4][HID];    // [wave][point][128]
  const int wv = threadIdx.x >> 6, lane = threadIdx.x & 63;
  const int cnt = min(((const int*)(ws + WS_RCNT))[0], RCAP);
  const int* rlist = (const int*)(ws + WS_RLIST);

  const int g = blockIdx.x * 4 + wv;    // wave's point-group (4 points)
  const int base = g * 4;
  if (base >= cnt) return;
  const int np = min(4, cnt - base);

  // ---- stage ve for up to 4 points (2 points per pass via half-waves)
#pragma unroll
  for (int pp = 0; pp < 4; pp += 2) {
    const int p = pp + (lane >> 5);      // local point 0..3
    const int e = lane & 31;
    const int ip = base + p;
    if (p < np) {
      const int pidx = rlist[ip];
      const int gidx = p2v[pidx];
      const float px = pts[pidx * 3 + 0];
      const float py = pts[pidx * 3 + 1];
      const float pz = pts[pidx * 3 + 2];
      velds[wv][p][e] = vox_emb[gidx * EMB + e] +
          fmaf(px, Wpts[e], fmaf(py, Wpts[EMB + e], pz * Wpts[2 * EMB + e]));
    }
  }

  // ---- L1: s[p] over k=0..31, W1 row loads shared by 4 points
  float s[4][2];
#pragma unroll
  for (int p = 0; p < 4; ++p) { s[p][0] = b1[lane]; s[p][1] = b1[lane + 64]; }
  for (int k = 0; k < EMB; ++k) {
    const float w0 = W1[k * HID + lane];
    const float w1 = W1[k * HID + lane + 64];
#pragma unroll
    for (int p = 0; p < 4; ++p) {
      const float x = velds[wv][p][k];
      s[p][0] = fmaf(x, w0, s[p][0]);
      s[p][1] = fmaf(x, w1, s[p][1]);
    }
  }
#pragma unroll
  for (int p = 0; p < 4; ++p) {
    h1lds[wv][p][lane] = fmaxf(s[p][0], 0.f);
    h1lds[wv][p][lane + 64] = fmaxf(s[p][1], 0.f);
  }

  // ---- L2: t[p] over k=0..127, W2 row loads shared by 4 points
  float t[4][2];
#pragma unroll
  for (int p = 0; p < 4; ++p) { t[p][0] = b2[lane]; t[p][1] = b2[lane + 64]; }
  for (int k = 0; k < HID; ++k) {
    const float w0 = W2[k * HID + lane];
    const float w1 = W2[k * HID + lane + 64];
#pragma unroll
    for (int p = 0; p < 4; ++p) {
      const float x = h1lds[wv][p][k];
      t[p][0] = fmaf(x, w0, t[p][0]);
      t[p][1] = fmaf(x, w1, t[p][1]);
    }
  }

  // ---- sigma per point (same per-point math/order as before)
  const float ws0 = Wsig[lane], ws1 = Wsig[lane + 64];
#pragma unroll
  for (int p = 0; p < 4; ++p) {
    if (p < np) {
      float sp = fmaf(fmaxf(t[p][0], 0.f), ws0, fmaxf(t[p][1], 0.f) * ws1);
      sp = wave_sum(sp);
      if (lane == 0) {
        const int pidx = rlist[base + p];
        ws[WS_PTOUT + 4 * pidx + 0] = sp + bsig[0];
      }
    }
  }
}

// ---------------- render ----------------
__device__ __forceinline__ float wave_prefix_excl(float v, int lane) {
  float inc = v;
#pragma unroll
  for (int off = 1; off < 64; off <<= 1) {
    float u = __shfl_up(inc, off, 64);
    if (lane >= off) inc += u;
  }
  return inc - v;
}

__global__ __launch_bounds__(256) void render_kernel(
    const float* __restrict__ t_vals, const float* __restrict__ dists,
    const int* __restrict__ p2v, const float* __restrict__ ws,
    float* __restrict__ out_rgb, float* __restrict__ out_disp,
    float* __restrict__ out_acc) {
  const int tid = threadIdx.x;
  const int ray = blockIdx.x * 4 + (tid >> 6);
  const int lane = tid & 63;
  const int pidx = ray * MAXS + lane;

  const int vidx = p2v[pidx];
  const bool hit = (__shfl(vidx, 0, 64) >= 0);
  if (!hit) {
    if (lane < 3) out_rgb[ray * 3 + lane] = 0.f;
    if (lane == 0) { out_disp[ray] = 0.f; out_acc[ray] = 0.f; }
    return;
  }
  const bool valid = vidx >= 0;

  const float4 pv = ((const float4*)(ws + WS_PTOUT))[pidx];
  const float fe = valid ? fmaxf(pv.x, 0.f) * dists[pidx] : 0.f;
  const float pref = wave_prefix_excl(fe, lane);
  const float T = __expf(-pref);
  const float w = (1.f - __expf(-fe)) * T;
  const float tv = t_vals[pidx];

  const float crgb0 = wave_sum(w * (pv.y + 1.f) * 0.5f);
  const float crgb1 = wave_sum(w * (pv.z + 1.f) * 0.5f);
  const float crgb2 = wave_sum(w * (pv.w + 1.f) * 0.5f);
  const float accs = wave_sum(w);
  const float depth = wave_sum(w * tv);

  if (lane == 0) {
    out_rgb[ray * 3 + 0] = crgb0;
    out_rgb[ray * 3 + 1] = crgb1;
    out_rgb[ray * 3 + 2] = crgb2;
    const float disp = 1.f / fmaxf(1e-10f, depth / fmaxf(accs, 1e-10f));
    out_disp[ray] = disp;
    out_acc[ray] = accs;
  }
}

extern "C" void kernel_launch(void* const* d_in, const int* in_sizes, int n_in,
                              void* d_out, int out_size, void* d_ws, size_t ws_size,
                              hipStream_t stream) {
  const float* rays_d  = (const float*)d_in[0];
  const float* pts     = (const float*)d_in[1];
  const float* t_vals  = (const float*)d_in[2];
  const float* dists   = (const float*)d_in[3];
  const int*   p2v     = (const int*)d_in[4];
  const float* vox_emb = (const float*)d_in[6];
  const float* Wpts    = (const float*)d_in[7];
  const float* W1      = (const float*)d_in[8];
  const float* b1      = (const float*)d_in[9];
  const float* W2      = (const float*)d_in[10];
  const float* b2      = (const float*)d_in[11];
  const float* Wsig    = (const float*)d_in[12];
  const float* bsig    = (const float*)d_in[13];
  const float* Wfeat   = (const float*)d_in[14];
  const float* bfeat   = (const float*)d_in[15];
  const float* Wc1     = (const float*)d_in[16];
  const float* bc1     = (const float*)d_in[17];
  const float* Wc2     = (const float*)d_in[18];
  const float* bc2     = (const float*)d_in[19];

  float* ws = (float*)d_ws;
  float* out = (float*)d_out;
  float* out_rgb = out;
  float* out_disp = out + NRAYS * 3;
  float* out_acc = out + NRAYS * 4;

  // prep threads: 8192 (Wcomb) + 2048 (WPE) + 64 (bcomb) + 2 = 10306
  hipLaunchKernelGGL(prep_kernel, dim3(41), dim3(256), 0, stream,
                     Wfeat, bfeat, Wc1, bc1, ws);
  hipLaunchKernelGGL(prep2_kernel, dim3(14), dim3(256), 0, stream, W1, W2, ws);
  hipLaunchKernelGGL(build_kernel, dim3(NRAYS / 16), dim3(1024), 0, stream,
                     rays_d, p2v, pts, ws);
  hipLaunchKernelGGL(mlp_mfma, dim3(NPTS / 64), dim3(256), 0, stream,
                     vox_emb, Wpts, b1, b2, Wsig, bsig, Wc2, bc2, ws);
  // repair: 1024 blocks x 4 waves x 4 pts = 16384 = RCAP exact cover
  hipLaunchKernelGGL(repair_kernel, dim3(1024), dim3(256), 0, stream,
                     pts, p2v, vox_emb, Wpts, W1, b1, W2, b2, Wsig, bsig, ws);
  hipLaunchKernelGGL(render_kernel, dim3(NRAYS / 4), dim3(256), 0, stream,
                     t_vals, dists, p2v, ws, out_rgb, out_disp, out_acc);
}

// Round 14
// 223.426 us; speedup vs baseline: 1.0288x; 1.0288x over previous
//
#include <hip/hip_runtime.h>
#include <stdint.h>

// NSVF render. Round-20 = REVERT to Round-18 (verified best, 225.0us).
//  R19's A/B isolated the LDS bank-conflict question: rotation swizzle cut
//  SQ_LDS_BANK_CONFLICT 8.52M -> 1.89M (4.5x, as derived) with NO dur
//  change (95.3 -> 97.5us) -- conflicts were fully hidden under latency
//  slack at 37% occupancy. Theory falsified; reverting to the verified
//  XOR-swizzle kernel to end on the best measured configuration.
//  Session: 260.5 -> 225.0us via repair grid-spread (-21us, R16), repair
//  weight-sharing (-3us, R17), N-split mlp + misc (-8us net). mlp_mfma is
//  a latency-bound fixpoint (8 structural attempts, 95-100us, all pipes
//  <35%); remaining non-mlp time is harness re-poison + ~20us small-kernel
//  floor.

#define NRAYS 8192
#define MAXS  64
#define EMB   32
#define HID   128
#define NPE   27
#define CH    64
#define NPTS  (NRAYS * MAXS)
#define RCAP  16384

// d_ws layout (float indices)
#define WS_WCOMB  0                        // [128][64] f32 (prep -> prep2)
#define WS_WPE    (WS_WCOMB + HID*CH)      // [32][64]
#define WS_BCOMB  (WS_WPE + 32*CH)         // [64]
#define WS_CCINIT (WS_BCOMB + CH)          // [8192][64]
#define WS_COUNTS (WS_CCINIT + NRAYS*CH)   // [8192] int (unused now)
#define WS_OFFS   (WS_COUNTS + NRAYS)      // [8192] int (unused now)
#define WS_TOTAL  (WS_OFFS + NRAYS)        // [1] int (atomic total)
#define WS_RCNT   (WS_TOTAL + 1)           // [1] int
#define WS_LIST   (WS_TOTAL + 4)           // [NPTS] int (16B aligned)
#define WS_PTOUT  (WS_LIST + NPTS)         // [NPTS] float4
#define WS_FRAGS  (WS_PTOUT + 4*NPTS)      // 56*2*64*4 ints
#define WS_RLIST  (WS_FRAGS + 56*2*64*4)   // [RCAP] int
#define WS_PTSC   (WS_RLIST + RCAP)        // [NPTS] float4 (16B aligned)

typedef __attribute__((ext_vector_type(8))) short bf16x8;
typedef __attribute__((ext_vector_type(4))) float f32x4;
union FI { int i[4]; int4 v; bf16x8 f; };

#define MFMA16(a, b, c) __builtin_amdgcn_mfma_f32_16x16x32_bf16(a, b, c, 0, 0, 0)

__device__ __forceinline__ f32x4 mfma3(bf16x8 ah, bf16x8 al, bf16x8 bh, bf16x8 bl,
                                       f32x4 c) {
  c = MFMA16(al, bh, c);
  c = MFMA16(ah, bl, c);
  c = MFMA16(ah, bh, c);
  return c;
}

// 2-pass: A is bf16-only, B stays hi/lo split
__device__ __forceinline__ f32x4 mfma2(bf16x8 ah, bf16x8 bh, bf16x8 bl, f32x4 c) {
  c = MFMA16(ah, bl, c);
  c = MFMA16(ah, bh, c);
  return c;
}

__device__ __forceinline__ void split8(const float* x, bf16x8& hi, bf16x8& lo) {
  FI H, L;
#pragma unroll
  for (int r = 0; r < 4; ++r) {
    unsigned u0 = __float_as_uint(x[2 * r]);
    unsigned u1 = __float_as_uint(x[2 * r + 1]);
    unsigned h0 = u0 & 0xffff0000u, h1 = u1 & 0xffff0000u;
    unsigned l0 = __float_as_uint(x[2 * r] - __uint_as_float(h0));
    unsigned l1 = __float_as_uint(x[2 * r + 1] - __uint_as_float(h1));
    H.i[r] = (int)((h0 >> 16) | (h1 & 0xffff0000u));
    L.i[r] = (int)((l0 >> 16) | (l1 & 0xffff0000u));
  }
  hi = H.f; lo = L.f;
}

// round-to-nearest-even bf16 (relu outputs: finite, non-NaN)
__device__ __forceinline__ unsigned short bf16rne(float v) {
  unsigned u = __float_as_uint(v);
  return (unsigned short)((u + 0x7fffu + ((u >> 16) & 1u)) >> 16);
}

// ---------------- prep: Wcomb f32 + PE tables + counter zero ----------------
__global__ __launch_bounds__(256) void prep_kernel(
    const float* __restrict__ Wfeat, const float* __restrict__ bfeat,
    const float* __restrict__ Wc1, const float* __restrict__ bc1,
    float* __restrict__ ws) {
  int idx = blockIdx.x * 256 + threadIdx.x;
  if (idx < HID * CH) {                        // Wcomb f32 (m-major), 8192-way
    int m = idx >> 6, j = idx & 63;
    float s = 0.f;
    for (int f = 0; f < HID; ++f) s = fmaf(Wfeat[m * HID + f], Wc1[f * CH + j], s);
    ws[WS_WCOMB + idx] = s;
    return;
  }
  idx -= HID * CH;
  if (idx < 32 * CH) {                         // WPE v-major [v][j]
    int v = idx >> 6, j = idx & 63;
    ws[WS_WPE + idx] = (v < NPE) ? Wc1[(HID + v) * CH + j] : 0.f;
    return;
  }
  idx -= 32 * CH;
  if (idx < CH) {                              // bcomb
    float s = bc1[idx];
    for (int f = 0; f < HID; ++f) s = fmaf(bfeat[f], Wc1[f * CH + idx], s);
    ws[WS_BCOMB + idx] = s;
    return;
  }
  idx -= CH;
  if (idx < 2) ((int*)(ws + WS_TOTAL))[idx] = 0;  // TOTAL (atomic base) + RCNT
}

// build bf16 hi/lo B-fragments: frag elem j of lane (n16,quad) = B[k0+j][n]
__global__ __launch_bounds__(256) void prep2_kernel(
    const float* __restrict__ W1, const float* __restrict__ W2,
    float* __restrict__ ws) {
  int t = blockIdx.x * 256 + threadIdx.x;
  if (t >= 56 * 64) return;
  const int fid = t >> 6, lane = t & 63;
  const int n16 = lane & 15, quad = lane >> 4;
  float x[8];
  if (fid < 8) {                       // L1: W1[k][n], K=32
    const int n = fid * 16 + n16, k0 = quad * 8;
#pragma unroll
    for (int j = 0; j < 8; ++j) x[j] = W1[(k0 + j) * HID + n];
  } else if (fid < 40) {               // L2: fid = 8 + nt*4 + s
    const int f = fid - 8, nt = f >> 2, s = f & 3;
    const int n = nt * 16 + n16, k0 = s * 32 + quad * 8;
#pragma unroll
    for (int j = 0; j < 8; ++j) x[j] = W2[(k0 + j) * HID + n];
  } else {                             // Wcomb: fid = 40 + nt*4 + s
    const int f = fid - 40, nt = f >> 2, s = f & 3;
    const int n = nt * 16 + n16, k0 = s * 32 + quad * 8;
#pragma unroll
    for (int j = 0; j < 8; ++j) x[j] = ws[WS_WCOMB + (k0 + j) * CH + n];
  }
  FI H, L;
#pragma unroll
  for (int r = 0; r < 4; ++r) {
    unsigned u0 = __float_as_uint(x[2 * r]);
    unsigned u1 = __float_as_uint(x[2 * r + 1]);
    unsigned h0 = u0 & 0xffff0000u, h1 = u1 & 0xffff0000u;
    unsigned l0 = __float_as_uint(x[2 * r] - __uint_as_float(h0));
    unsigned l1 = __float_as_uint(x[2 * r + 1] - __uint_as_float(h1));
    H.i[r] = (int)((h0 >> 16) | (h1 & 0xffff0000u));
    L.i[r] = (int)((l0 >> 16) | (l1 & 0xffff0000u));
  }
  int4* o = (int4*)(ws + WS_FRAGS);
  o[(fid * 2 + 0) * 64 + lane] = H.v;
  o[(fid * 2 + 1) * 64 + lane] = L.v;
}

// ------- fused build: ballot count + block scan + 1 atomic/block +
//         compacted list/ptsc gather + per-ray view-PE -------------------
__global__ __launch_bounds__(1024) void build_kernel(
    const float* __restrict__ rays_d, const int* __restrict__ p2v,
    const float* __restrict__ pts, float* __restrict__ ws) {
  __shared__ int wcnt[16];
  __shared__ int wbase[16];
  const int tid = threadIdx.x;
  const int wv = tid >> 6, lane = tid & 63;
  const int ray = blockIdx.x * 16 + wv;
  const int pidx = ray * MAXS + lane;
  const int gidx = p2v[pidx];
  const bool valid = gidx >= 0;
  const unsigned long long ball = __ballot(valid);
  const int cnt = __popcll(ball);
  const int rank = __popcll(ball & ((1ull << lane) - 1ull));
  if (lane == 0) wcnt[wv] = cnt;
  __syncthreads();
  if (tid < 16) {                      // wave 0, lanes 0..15: scan 16 counts
    const int c = wcnt[tid];
    int inc = c;
#pragma unroll
    for (int off = 1; off < 16; off <<= 1) {
      const int u = __shfl_up(inc, off, 64);
      if (tid >= off) inc += u;
    }
    const int excl = inc - c;
    const int btot = __shfl(inc, 15, 64);
    int gbase = 0;
    if (tid == 0) gbase = atomicAdd((int*)(ws + WS_TOTAL), btot);
    gbase = __shfl(gbase, 0, 64);
    wbase[tid] = gbase + excl;
  }
  __syncthreads();
  if (valid) {
    const int slot = wbase[wv] + rank;
    ((int*)(ws + WS_LIST))[slot] = pidx;
    float4 pc;
    pc.x = pts[pidx * 3 + 0];
    pc.y = pts[pidx * 3 + 1];
    pc.z = pts[pidx * 3 + 2];
    pc.w = __int_as_float(gidx);
    ((float4*)(ws + WS_PTSC))[slot] = pc;
  }

  // per-ray view-PE -> ccinit[ray][lane] (identical math to count_pe)
  const float d0 = rays_d[ray * 3 + 0];
  const float d1 = rays_d[ray * 3 + 1];
  const float d2 = rays_d[ray * 3 + 2];
  float vemb[NPE];
  vemb[0] = d0; vemb[1] = d1; vemb[2] = d2;
#pragma unroll
  for (int i = 0; i < 3; ++i) {
    const float di = (i == 0) ? d0 : (i == 1) ? d1 : d2;
#pragma unroll
    for (int l = 0; l < 4; ++l) {
      const float ang = di * (float)(1 << l);
      vemb[3 + i * 4 + l] = __sinf(ang);
      vemb[3 + 12 + i * 4 + l] = __cosf(ang);
    }
  }
  float s = ws[WS_BCOMB + lane];
  const float* wpe = ws + WS_WPE;
#pragma unroll
  for (int vv = 0; vv < NPE; ++vv) s = fmaf(vemb[vv], wpe[vv * CH + lane], s);
  ws[WS_CCINIT + ray * CH + lane] = s;
}

// ---------------- MFMA MLP (4 waves, M=64, N-split) — R14 verified ----------
__device__ __forceinline__ void ve_frag(const float* __restrict__ vox_emb,
                                        const float* __restrict__ Wpts,
                                        float4 pc, int quad,
                                        bf16x8& hi, bf16x8& lo) {
  float x[8];
  const int gidx = __float_as_int(pc.w);
  const float4* vr = (const float4*)vox_emb + gidx * 8 + quad * 2;
  const float4 va = vr[0], vb = vr[1];
  const float px = pc.x, py = pc.y, pz = pc.z;
  const float4* wp = (const float4*)Wpts;
  const float4 wa0 = wp[quad * 2 + 0], wa1 = wp[quad * 2 + 1];
  const float4 wb0 = wp[8 + quad * 2 + 0], wb1 = wp[8 + quad * 2 + 1];
  const float4 wc0 = wp[16 + quad * 2 + 0], wc1 = wp[16 + quad * 2 + 1];
  x[0] = va.x + fmaf(px, wa0.x, fmaf(py, wb0.x, pz * wc0.x));
  x[1] = va.y + fmaf(px, wa0.y, fmaf(py, wb0.y, pz * wc0.y));
  x[2] = va.z + fmaf(px, wa0.z, fmaf(py, wb0.z, pz * wc0.z));
  x[3] = va.w + fmaf(px, wa0.w, fmaf(py, wb0.w, pz * wc0.w));
  x[4] = vb.x + fmaf(px, wa1.x, fmaf(py, wb1.x, pz * wc1.x));
  x[5] = vb.y + fmaf(px, wa1.y, fmaf(py, wb1.y, pz * wc1.y));
  x[6] = vb.z + fmaf(px, wa1.z, fmaf(py, wb1.z, pz * wc1.z));
  x[7] = vb.w + fmaf(px, wa1.w, fmaf(py, wb1.w, pz * wc1.w));
  split8(x, hi, lo);
}

// bf16 activation LDS: 64 rows x 136 shorts; swizzled 16B granules
// element (row,k) stored at row*136 + (((k>>3) ^ (row&7))<<3) + (k&7)
#define SROW 136

__global__ __launch_bounds__(256, 4) void mlp_mfma(
    const float* __restrict__ vox_emb, const float* __restrict__ Wpts,
    const float* __restrict__ b1, const float* __restrict__ b2,
    const float* __restrict__ Wsig, const float* __restrict__ bsig,
    const float* __restrict__ Wc2, const float* __restrict__ bc2,
    float* __restrict__ ws) {
  __shared__ __align__(16) unsigned short alds[64 * SROW];
  __shared__ float sgp[4][64];
  __shared__ __align__(16) float4 rgbp[4][64];
  const int tid = threadIdx.x;
  const int wave = tid >> 6, lane = tid & 63;
  const int n16 = lane & 15, quad = lane >> 4;
  const int total = ((const int*)(ws + WS_TOTAL))[0];
  const int base = blockIdx.x * 64;
  if (base >= total) return;
  const int* list = (const int*)(ws + WS_LIST);

  // point ids + coords for all 4 m-slots (block covers 64 points)
  int pidx[4]; float4 pc[4];
#pragma unroll
  for (int m = 0; m < 4; ++m) {
    const int slot = min(base + m * 16 + n16, total - 1);
    pidx[m] = list[slot];
    pc[m] = ((const float4*)(ws + WS_PTSC))[slot];
  }
  const int4* fb = (const int4*)(ws + WS_FRAGS);
  const int nt0 = 2 * wave, nt1 = nt0 + 1;   // this wave's L1/L2 N-slice

  // ---- L1 B frags for this wave's 2 nt tiles (hi+lo)
  int4 B1[4];
  B1[0] = fb[(nt0 * 2 + 0) * 64 + lane];
  B1[1] = fb[(nt0 * 2 + 1) * 64 + lane];
  B1[2] = fb[(nt1 * 2 + 0) * 64 + lane];
  B1[3] = fb[(nt1 * 2 + 1) * 64 + lane];

  // ---- A (ve) fragments for all 4 m-slots (gathers fly with B1)
  bf16x8 ah[4], al[4];
#pragma unroll
  for (int m = 0; m < 4; ++m) ve_frag(vox_emb, Wpts, pc[m], quad, ah[m], al[m]);

  // ---- prefetch L2 s=0
  int4 BL[4];
  BL[0] = fb[((8 + nt0 * 4) * 2 + 0) * 64 + lane];
  BL[1] = fb[((8 + nt0 * 4) * 2 + 1) * 64 + lane];
  BL[2] = fb[((8 + nt1 * 4) * 2 + 0) * 64 + lane];
  BL[3] = fb[((8 + nt1 * 4) * 2 + 1) * 64 + lane];

  // ---- L1: h1[:, wave cols] for 64 pts (3-pass, A = f32 split)
  f32x4 h[4][2];
  {
    const float ba = b1[nt0 * 16 + n16], bb = b1[nt1 * 16 + n16];
#pragma unroll
    for (int m = 0; m < 4; ++m) {
      h[m][0] = (f32x4){ba, ba, ba, ba};
      h[m][1] = (f32x4){bb, bb, bb, bb};
    }
  }
  {
    FI H0, L0, H1, L1v;
    H0.v = B1[0]; L0.v = B1[1]; H1.v = B1[2]; L1v.v = B1[3];
#pragma unroll
    for (int m = 0; m < 4; ++m) {
      h[m][0] = mfma3(ah[m], al[m], H0.f, L0.f, h[m][0]);
      h[m][1] = mfma3(ah[m], al[m], H1.f, L1v.f, h[m][1]);
    }
  }
#pragma unroll
  for (int m = 0; m < 4; ++m)
#pragma unroll
    for (int j = 0; j < 2; ++j) {
      const int nt = nt0 + j;
#pragma unroll
      for (int r = 0; r < 4; ++r) {
        const float v = fmaxf(h[m][j][r], 0.f);
        const int row = m * 16 + quad * 4 + r;
        const int gk = ((2 * nt + (n16 >> 3)) ^ (row & 7)) << 3;
        alds[row * SROW + gk + (n16 & 7)] = bf16rne(v);
      }
    }
  __syncthreads();   // h1 complete (all cols, all rows)

  // ---- L2: g[:, wave cols] for 64 pts, A = bf16 from LDS, K=128
  f32x4 g[4][2];
  {
    const float ba = b2[nt0 * 16 + n16], bb = b2[nt1 * 16 + n16];
#pragma unroll
    for (int m = 0; m < 4; ++m) {
      g[m][0] = (f32x4){ba, ba, ba, ba};
      g[m][1] = (f32x4){bb, bb, bb, bb};
    }
  }
  const int t7 = n16 & 7;
#pragma unroll
  for (int s = 0; s < 4; ++s) {
    const int gq = ((4 * s + quad) ^ t7) << 3;
    FI H0, L0, H1, L1v;
    H0.v = BL[0]; L0.v = BL[1]; H1.v = BL[2]; L1v.v = BL[3];
#pragma unroll
    for (int m = 0; m < 4; ++m) {
      const bf16x8 A = *(const bf16x8*)&alds[(m * 16 + n16) * SROW + gq];
      g[m][0] = mfma2(A, H0.f, L0.f, g[m][0]);
      g[m][1] = mfma2(A, H1.f, L1v.f, g[m][1]);
    }
    if (s < 3) {
      BL[0] = fb[((8 + nt0 * 4 + s + 1) * 2 + 0) * 64 + lane];
      BL[1] = fb[((8 + nt0 * 4 + s + 1) * 2 + 1) * 64 + lane];
      BL[2] = fb[((8 + nt1 * 4 + s + 1) * 2 + 0) * 64 + lane];
      BL[3] = fb[((8 + nt1 * 4 + s + 1) * 2 + 1) * 64 + lane];
    }
  }

  // ---- overlap global work with the pre-h2 barrier:
  // color B (nt = wave, all 4 s), pm shuffles, ccinit gathers
  int4 BC[8];
#pragma unroll
  for (int s = 0; s < 4; ++s) {
    BC[2 * s]     = fb[((40 + wave * 4 + s) * 2 + 0) * 64 + lane];
    BC[2 * s + 1] = fb[((40 + wave * 4 + s) * 2 + 1) * 64 + lane];
  }
  int pm[4][4];
#pragma unroll
  for (int m = 0; m < 4; ++m)
#pragma unroll
    for (int r = 0; r < 4; ++r)
      pm[m][r] = __shfl(pidx[m], quad * 4 + r, 64);
  f32x4 cacc[4];
#pragma unroll
  for (int m = 0; m < 4; ++m)
#pragma unroll
    for (int r = 0; r < 4; ++r)
      cacc[m][r] = ws[WS_CCINIT + (pm[m][r] >> 6) * CH + wave * 16 + n16];

  __syncthreads();   // all waves done READING h1 -> safe to overwrite with h2

  // ---- sigma partials (this wave's 32 cols) + write h2
  float sgv[4][4];
#pragma unroll
  for (int m = 0; m < 4; ++m)
#pragma unroll
    for (int r = 0; r < 4; ++r) sgv[m][r] = 0.f;
  {
    const float sv0 = Wsig[nt0 * 16 + n16], sv1 = Wsig[nt1 * 16 + n16];
#pragma unroll
    for (int m = 0; m < 4; ++m)
#pragma unroll
      for (int j = 0; j < 2; ++j) {
        const int nt = nt0 + j;
        const float sv = j ? sv1 : sv0;
#pragma unroll
        for (int r = 0; r < 4; ++r) {
          const float v = fmaxf(g[m][j][r], 0.f);
          sgv[m][r] = fmaf(v, sv, sgv[m][r]);
          const int row = m * 16 + quad * 4 + r;
          const int gk = ((2 * nt + (n16 >> 3)) ^ (row & 7)) << 3;
          alds[row * SROW + gk + (n16 & 7)] = bf16rne(v);
        }
      }
  }
#pragma unroll
  for (int mask = 1; mask < 16; mask <<= 1)
#pragma unroll
    for (int m = 0; m < 4; ++m)
#pragma unroll
      for (int r = 0; r < 4; ++r)
        sgv[m][r] += __shfl_xor(sgv[m][r], mask, 64);
  if (n16 == 0) {
#pragma unroll
    for (int m = 0; m < 4; ++m)
#pragma unroll
      for (int r = 0; r < 4; ++r)
        sgp[wave][m * 16 + quad * 4 + r] = sgv[m][r];
  }
  __syncthreads();   // h2 + sigma partials ready

  // ---- color: cc[:, wave*16..+16) = ccinit + h2 @ Wcomb slice
#pragma unroll
  for (int s = 0; s < 4; ++s) {
    const int gq = ((4 * s + quad) ^ t7) << 3;
    FI H, L;
    H.v = BC[2 * s]; L.v = BC[2 * s + 1];
#pragma unroll
    for (int m = 0; m < 4; ++m) {
      const bf16x8 A = *(const bf16x8*)&alds[(m * 16 + n16) * SROW + gq];
      cacc[m] = mfma2(A, H.f, L.f, cacc[m]);
    }
  }

  // ---- rgb partials from this wave's 16 cols
  {
    const int j = wave * 16 + n16;
    const float w0 = Wc2[j * 3 + 0], w1c = Wc2[j * 3 + 1], w2c = Wc2[j * 3 + 2];
#pragma unroll
    for (int m = 0; m < 4; ++m) {
      float c0[4], c1[4], c2[4];
#pragma unroll
      for (int r = 0; r < 4; ++r) {
        const float cv = fmaxf(cacc[m][r], 0.f);
        c0[r] = cv * w0; c1[r] = cv * w1c; c2[r] = cv * w2c;
      }
#pragma unroll
      for (int mask = 1; mask < 16; mask <<= 1)
#pragma unroll
        for (int r = 0; r < 4; ++r) {
          c0[r] += __shfl_xor(c0[r], mask, 64);
          c1[r] += __shfl_xor(c1[r], mask, 64);
          c2[r] += __shfl_xor(c2[r], mask, 64);
        }
      if (n16 == 0) {
#pragma unroll
        for (int r = 0; r < 4; ++r)
          rgbp[wave][m * 16 + quad * 4 + r] = make_float4(c0[r], c1[r], c2[r], 0.f);
      }
    }
  }
  __syncthreads();   // rgb partials ready

  // ---- final: wave owns its own m = wave points
  const int pidw = (wave == 0) ? pidx[0] : (wave == 1) ? pidx[1]
                 : (wave == 2) ? pidx[2] : pidx[3];
  int pmw[4];
#pragma unroll
  for (int r = 0; r < 4; ++r) pmw[r] = __shfl(pidw, quad * 4 + r, 64);

  if (n16 == 0) {
    const float bs = bsig[0];
    const float bcr = bc2[0], bcg = bc2[1], bcb = bc2[2];
#pragma unroll
    for (int r = 0; r < 4; ++r) {
      const int ptl = wave * 16 + quad * 4 + r;
      if (base + ptl < total) {
        const int pid = pmw[r];
        const float sig = sgp[0][ptl] + sgp[1][ptl] + sgp[2][ptl] + sgp[3][ptl] + bs;
        const float4 r0 = rgbp[0][ptl], r1 = rgbp[1][ptl];
        const float4 r2 = rgbp[2][ptl], r3 = rgbp[3][ptl];
        ((float4*)(ws + WS_PTOUT))[pid] = make_float4(
            sig,
            r0.x + r1.x + r2.x + r3.x + bcr,
            r0.y + r1.y + r2.y + r3.y + bcg,
            r0.z + r1.z + r2.z + r3.z + bcb);
        if (fabsf(sig) < 0.006f) {
          const int ri = atomicAdd((int*)(ws + WS_RCNT), 1);
          if (ri < RCAP) ((int*)(ws + WS_RLIST))[ri] = pid;
        }
      }
    }
  }
}

// ------- sigma repair: wave-per-4-points, shared W1/W2 row loads -------
__device__ __forceinline__ float wave_sum(float v) {
#pragma unroll
  for (int off = 32; off > 0; off >>= 1) v += __shfl_down(v, off, 64);
  return v;
}

__global__ __launch_bounds__(256) void repair_kernel(
    const float* __restrict__ pts, const int* __restrict__ p2v,
    const float* __restrict__ vox_emb, const float* __restrict__ Wpts,
    const float* __restrict__ W1, const float* __restrict__ b1,
    const float* __restrict__ W2, const float* __restrict__ b2,
    const float* __restrict__ Wsig, const float* __restrict__ bsig,
    float* __restrict__ ws) {
  // per-wave LDS slices (wave-coherent, no block barriers needed)
  __shared__ float velds[4][4][EMB];    // [wave][point][32]
  __shared__ float h1lds[4][4][HID];    // [wave][point][128]
  const int wv = threadIdx.x >> 6, lane = threadIdx.x & 63;
  const int cnt = min(((const int*)(ws + WS_RCNT))[0], RCAP);
  const int* rlist = (const int*)(ws + WS_RLIST);

  const int g = blockIdx.x * 4 + wv;    // wave's point-group (4 points)
  const int base = g * 4;
  if (base >= cnt) return;
  const int np = min(4, cnt - base);

  // ---- stage ve for up to 4 points (2 points per pass via half-waves)
#pragma unroll
  for (int pp = 0; pp < 4; pp += 2) {
    const int p = pp + (lane >> 5);      // local point 0..3
    const int e = lane & 31;
    const int ip = base + p;
    if (p < np) {
      const int pidx = rlist[ip];
      const int gidx = p2v[pidx];
      const float px = pts[pidx * 3 + 0];
      const float py = pts[pidx * 3 + 1];
      const float pz = pts[pidx * 3 + 2];
      velds[wv][p][e] = vox_emb[gidx * EMB + e] +
          fmaf(px, Wpts[e], fmaf(py, Wpts[EMB + e], pz * Wpts[2 * EMB + e]));
    }
  }

  // ---- L1: s[p] over k=0..31, W1 row loads shared by 4 points
  float s[4][2];
#pragma unroll
  for (int p = 0; p < 4; ++p) { s[p][0] = b1[lane]; s[p][1] = b1[lane + 64]; }
  for (int k = 0; k < EMB; ++k) {
    const float w0 = W1[k * HID + lane];
    const float w1 = W1[k * HID + lane + 64];
#pragma unroll
    for (int p = 0; p < 4; ++p) {
      const float x = velds[wv][p][k];
      s[p][0] = fmaf(x, w0, s[p][0]);
      s[p][1] = fmaf(x, w1, s[p][1]);
    }
  }
#pragma unroll
  for (int p = 0; p < 4; ++p) {
    h1lds[wv][p][lane] = fmaxf(s[p][0], 0.f);
    h1lds[wv][p][lane + 64] = fmaxf(s[p][1], 0.f);
  }

  // ---- L2: t[p] over k=0..127, W2 row loads shared by 4 points
  float t[4][2];
#pragma unroll
  for (int p = 0; p < 4; ++p) { t[p][0] = b2[lane]; t[p][1] = b2[lane + 64]; }
  for (int k = 0; k < HID; ++k) {
    const float w0 = W2[k * HID + lane];
    const float w1 = W2[k * HID + lane + 64];
#pragma unroll
    for (int p = 0; p < 4; ++p) {
      const float x = h1lds[wv][p][k];
      t[p][0] = fmaf(x, w0, t[p][0]);
      t[p][1] = fmaf(x, w1, t[p][1]);
    }
  }

  // ---- sigma per point (same per-point math/order as before)
  const float ws0 = Wsig[lane], ws1 = Wsig[lane + 64];
#pragma unroll
  for (int p = 0; p < 4; ++p) {
    if (p < np) {
      float sp = fmaf(fmaxf(t[p][0], 0.f), ws0, fmaxf(t[p][1], 0.f) * ws1);
      sp = wave_sum(sp);
      if (lane == 0) {
        const int pidx = rlist[base + p];
        ws[WS_PTOUT + 4 * pidx + 0] = sp + bsig[0];
      }
    }
  }
}

// ---------------- render ----------------
__device__ __forceinline__ float wave_prefix_excl(float v, int lane) {
  float inc = v;
#pragma unroll
  for (int off = 1; off < 64; off <<= 1) {
    float u = __shfl_up(inc, off, 64);
    if (lane >= off) inc += u;
  }
  return inc - v;
}

__global__ __launch_bounds__(256) void render_kernel(
    const float* __restrict__ t_vals, const float* __restrict__ dists,
    const int* __restrict__ p2v, const float* __restrict__ ws,
    float* __restrict__ out_rgb, float* __restrict__ out_disp,
    float* __restrict__ out_acc) {
  const int tid = threadIdx.x;
  const int ray = blockIdx.x * 4 + (tid >> 6);
  const int lane = tid & 63;
  const int pidx = ray * MAXS + lane;

  const int vidx = p2v[pidx];
  const bool hit = (__shfl(vidx, 0, 64) >= 0);
  if (!hit) {
    if (lane < 3) out_rgb[ray * 3 + lane] = 0.f;
    if (lane == 0) { out_disp[ray] = 0.f; out_acc[ray] = 0.f; }
    return;
  }
  const bool valid = vidx >= 0;

  const float4 pv = ((const float4*)(ws + WS_PTOUT))[pidx];
  const float fe = valid ? fmaxf(pv.x, 0.f) * dists[pidx] : 0.f;
  const float pref = wave_prefix_excl(fe, lane);
  const float T = __expf(-pref);
  const float w = (1.f - __expf(-fe)) * T;
  const float tv = t_vals[pidx];

  const float crgb0 = wave_sum(w * (pv.y + 1.f) * 0.5f);
  const float crgb1 = wave_sum(w * (pv.z + 1.f) * 0.5f);
  const float crgb2 = wave_sum(w * (pv.w + 1.f) * 0.5f);
  const float accs = wave_sum(w);
  const float depth = wave_sum(w * tv);

  if (lane == 0) {
    out_rgb[ray * 3 + 0] = crgb0;
    out_rgb[ray * 3 + 1] = crgb1;
    out_rgb[ray * 3 + 2] = crgb2;
    const float disp = 1.f / fmaxf(1e-10f, depth / fmaxf(accs, 1e-10f));
    out_disp[ray] = disp;
    out_acc[ray] = accs;
  }
}

extern "C" void kernel_launch(void* const* d_in, const int* in_sizes, int n_in,
                              void* d_out, int out_size, void* d_ws, size_t ws_size,
                              hipStream_t stream) {
  const float* rays_d  = (const float*)d_in[0];
  const float* pts     = (const float*)d_in[1];
  const float* t_vals  = (const float*)d_in[2];
  const float* dists   = (const float*)d_in[3];
  const int*   p2v     = (const int*)d_in[4];
  const float* vox_emb = (const float*)d_in[6];
  const float* Wpts    = (const float*)d_in[7];
  const float* W1      = (const float*)d_in[8];
  const float* b1      = (const float*)d_in[9];
  const float* W2      = (const float*)d_in[10];
  const float* b2      = (const float*)d_in[11];
  const float* Wsig    = (const float*)d_in[12];
  const float* bsig    = (const float*)d_in[13];
  const float* Wfeat   = (const float*)d_in[14];
  const float* bfeat   = (const float*)d_in[15];
  const float* Wc1     = (const float*)d_in[16];
  const float* bc1     = (const float*)d_in[17];
  const float* Wc2     = (const float*)d_in[18];
  const float* bc2     = (const float*)d_in[19];

  float* ws = (float*)d_ws;
  float* out = (float*)d_out;
  float* out_rgb = out;
  float* out_disp = out + NRAYS * 3;
  float* out_acc = out + NRAYS * 4;

  // prep threads: 8192 (Wcomb) + 2048 (WPE) + 64 (bcomb) + 2 = 10306
  hipLaunchKernelGGL(prep_kernel, dim3(41), dim3(256), 0, stream,
                     Wfeat, bfeat, Wc1, bc1, ws);
  hipLaunchKernelGGL(prep2_kernel, dim3(14), dim3(256), 0, stream, W1, W2, ws);
  hipLaunchKernelGGL(build_kernel, dim3(NRAYS / 16), dim3(1024), 0, stream,
                     rays_d, p2v, pts, ws);
  hipLaunchKernelGGL(mlp_mfma, dim3(NPTS / 64), dim3(256), 0, stream,
                     vox_emb, Wpts, b1, b2, Wsig, bsig, Wc2, bc2, ws);
  // repair: 1024 blocks x 4 waves x 4 pts = 16384 = RCAP exact cover
  hipLaunchKernelGGL(repair_kernel, dim3(1024), dim3(256), 0, stream,
                     pts, p2v, vox_emb, Wpts, W1, b1, W2, b2, Wsig, bsig, ws);
  hipLaunchKernelGGL(render_kernel, dim3(NRAYS / 4), dim3(256), 0, stream,
                     t_vals, dists, p2v, ws, out_rgb, out_disp, out_acc);
}